// Round 17
// baseline (929.704 us; speedup 1.0000x reference)
//
#include <hip/hip_runtime.h>

typedef __attribute__((ext_vector_type(8))) short bh8;    // 8 bf16 = 4 VGPR
typedef __attribute__((ext_vector_type(4))) float f4v;    // 16x16 MFMA acc
typedef __attribute__((ext_vector_type(2))) long lg2;     // 16B fp8 frag pair

constexpr int VOC = 65;
constexpr int NL  = 6;
constexpr int Mrow = 4096;   // B*T
constexpr float LOG2E = 1.44269504088896f;

__device__ inline float b2f(unsigned short u) {
  union { unsigned int i; float f; } x; x.i = ((unsigned int)u) << 16; return x.f;
}
__device__ inline unsigned short f2b(float f) {
  union { float f; unsigned int i; } x; x.f = f;
  return (unsigned short)((x.i + 0x7FFFu + ((x.i >> 16) & 1u)) >> 16);
}
__device__ inline unsigned char f2e4m3(float v) {
  return (unsigned char)(__builtin_amdgcn_cvt_pk_fp8_f32(v, v, 0, false) & 0xFF);
}
__device__ inline unsigned int pk4_e4m3(float a, float b, float c, float d) {
  int v = __builtin_amdgcn_cvt_pk_fp8_f32(a, b, 0, false);
  v = __builtin_amdgcn_cvt_pk_fp8_f32(c, d, v, true);
  return (unsigned int)v;
}
// k-permutation within each 128-block: [ks(2)|lh(2)|b(3)] -> [lh|ks|b].
__device__ inline int perm128(int k) {
  return (k & ~127) | (k & 7) | (((k >> 5) & 3) << 3) | (((k >> 3) & 3) << 5);
}
__device__ inline void gld16(const void* g, void* l) {
  __builtin_amdgcn_global_load_lds(
      (const __attribute__((address_space(1))) unsigned int*)g,
      (__attribute__((address_space(3))) unsigned int*)l, 16, 0, 0);
}
// swizzled LDS b128 read from a row-major [rows][64 bf16] tile (128 B rows)
__device__ inline bh8 lds_swz(const unsigned short* base, int row, int colbyte) {
  int off = row * 128 + (colbyte ^ ((row & 7) << 4));
  return *(const bh8*)((const char*)base + off);
}
__device__ inline f4v mfma16(bh8 a, bh8 b, f4v c) {
  return __builtin_amdgcn_mfma_f32_16x16x32_bf16(a, b, c, 0, 0, 0);
}
__device__ inline f4v mfma8(long a, long b, f4v c) {
  return __builtin_amdgcn_mfma_f32_16x16x32_fp8_fp8(a, b, c, 0, 0, 0);
}
#define WAITV(n) asm volatile("s_waitcnt vmcnt(" #n ")" ::: "memory")
#define LGKM0 asm volatile("s_waitcnt lgkmcnt(0)" ::: "memory")
#define LGKM8 asm volatile("s_waitcnt lgkmcnt(8)" ::: "memory")
#define SBAR0 __builtin_amdgcn_sched_barrier(0)
#define BAR __builtin_amdgcn_s_barrier()

// ---------------------------------------------------------- fused weight prep
__device__ inline void wt_conv_dev(float (*t)[33], const float* __restrict__ src,
    unsigned short* __restrict__ dst, int K, int N, int bx, int by) {
  int k0 = bx * 32, n0 = by * 32, tid = threadIdx.x;
#pragma unroll
  for (int i = 0; i < 4; ++i) {
    int idx = tid + i * 256;
    int kr = idx >> 5, nc = idx & 31;
    t[kr][nc] = (n0 + nc < N) ? src[(size_t)(k0 + kr) * N + n0 + nc] : 0.f;
  }
  __syncthreads();
#pragma unroll
  for (int i = 0; i < 4; ++i) {
    int idx = tid + i * 256;
    int nr = idx >> 5, kc = idx & 31;
    dst[(size_t)(n0 + nr) * K + k0 + kc] = f2b(t[kc][nr]);
  }
}
__device__ inline void wt_conv8_dev(float (*t)[33], const float* __restrict__ src,
    unsigned char* __restrict__ dst, int K, int N, int bx, int by) {
  int k0 = bx * 32, n0 = by * 32, tid = threadIdx.x;
#pragma unroll
  for (int i = 0; i < 4; ++i) {
    int idx = tid + i * 256;
    int kr = idx >> 5, nc = idx & 31;
    t[kr][nc] = src[(size_t)(k0 + kr) * N + n0 + nc];
  }
  __syncthreads();
#pragma unroll
  for (int i = 0; i < 4; ++i) {
    int idx = tid + i * 256;
    int nr = idx >> 5, kc = idx & 31;
    dst[(size_t)(n0 + nr) * K + perm128(k0 + kc)] = f2e4m3(t[kc][nr] * 16.f);
  }
}

// One dispatch does ALL weight conversions + bias packing.
__global__ __launch_bounds__(256) void prep_all(
    const float* __restrict__ Wq, const float* __restrict__ Wk,
    const float* __restrict__ Wv, const float* __restrict__ W1,
    const float* __restrict__ W2, const float* __restrict__ Wf,
    const float* __restrict__ bq, const float* __restrict__ bk,
    const float* __restrict__ bv, const float* __restrict__ bf,
    unsigned short* __restrict__ WqkvT, unsigned char* __restrict__ W1T8,
    unsigned char* __restrict__ W2T8, unsigned short* __restrict__ WfT,
    float* __restrict__ bqkv, float* __restrict__ bfp) {
  __shared__ float t[32][33];
  int bid = blockIdx.x;
  if (bid < 1024) {
    wt_conv_dev(t, Wq, WqkvT, 1024, 1024, bid & 31, bid >> 5);
  } else if (bid < 2048) {
    int lb = bid - 1024;
    wt_conv_dev(t, Wk, WqkvT + 1024 * 1024, 1024, 1024, lb & 31, lb >> 5);
  } else if (bid < 3072) {
    int lb = bid - 2048;
    wt_conv_dev(t, Wv, WqkvT + 2048 * 1024, 1024, 1024, lb & 31, lb >> 5);
  } else if (bid < 7168) {
    int lb = bid - 3072;                      // W1: dim3(32,128)
    wt_conv8_dev(t, W1, W1T8, 1024, 4096, lb & 31, lb >> 5);
  } else if (bid < 11264) {
    int lb = bid - 7168;                      // W2: dim3(128,32)
    wt_conv8_dev(t, W2, W2T8, 4096, 1024, lb & 127, lb >> 7);
  } else if (bid < 11392) {
    int lb = bid - 11264;                     // Wf: dim3(32,4), N=65 guard
    wt_conv_dev(t, Wf, WfT, 1024, VOC, lb & 31, lb >> 5);
  } else {
    int i = (bid - 11392) * 256 + threadIdx.x;
    if (i < 1024) bqkv[i] = bq[i];
    else if (i < 2048) bqkv[i] = bk[i - 1024];
    else if (i < 3072) bqkv[i] = bv[i - 2048];
    else if (i < 3200) bfp[i - 3072] = (i - 3072 < VOC) ? bf[i - 3072] : 0.f;
  }
}

// ---------------------------------------------------------------- embedding
__global__ __launch_bounds__(256) void embed_bf(const int* __restrict__ tok,
    const float* __restrict__ Wtok, const float* __restrict__ Wpos,
    unsigned short* __restrict__ Xb) {
  int bt = blockIdx.x, t = bt & 1023, tid = threadIdx.x;
  int id = tok[bt];
  float4 a = ((const float4*)(Wtok + (size_t)id * 1024))[tid];
  float4 p = ((const float4*)(Wpos + (size_t)t * 1024))[tid];
  ushort4 o;
  o.x = f2b(a.x + p.x); o.y = f2b(a.y + p.y);
  o.z = f2b(a.z + p.z); o.w = f2b(a.w + p.w);
  ((ushort4*)(Xb + (size_t)bt * 1024))[tid] = o;
}

// ---------------------- QKV GEMM: 256x192 tile, 8-phase bf16, grid 256 EXACT
// Q columns scaled by log2(e)/32 -> attention scores land in exp2 domain.
__global__ __launch_bounds__(512, 1) void gemm192(
    const unsigned short* __restrict__ A, const unsigned short* __restrict__ Bt,
    const float* __restrict__ bias, unsigned short* __restrict__ Cout,
    unsigned short* __restrict__ Vtout, long N, long K,
    int MT, int CM, int CN) {
  __shared__ unsigned short Abuf[2][256 * 64];   // 64KB
  __shared__ unsigned short Bbuf[2][192 * 64];   // 48KB
  const int tid = threadIdx.x, lane = tid & 63, w = tid >> 6;
  const int wr = w >> 2, wc = w & 3;             // 2M x 4N waves
  const int lr = lane & 15, lh = lane >> 4, lh4 = lh * 4;

  const int x = (int)blockIdx.x & 7, j = (int)blockIdx.x >> 3;
  const int gM = MT / CM;
  const int rowT = (x % gM) * CM + (j % CM);
  const int colT = (x / gM) * CN + (j / CM);
  const long row0 = (long)rowT * 256, col0 = (long)colT * 192;

  f4v acc[8][3];
#pragma unroll
  for (int i = 0; i < 8; ++i)
#pragma unroll
    for (int jj = 0; jj < 3; ++jj) acc[i][jj] = f4v{0.f, 0.f, 0.f, 0.f};

  const int rg = tid >> 3, sIdx = tid & 7;
  const int ch = sIdx ^ (rg & 7);
  const unsigned short* Ap = A + (row0 + rg) * K + ch * 8;
  const unsigned short* Bp = Bt + (col0 + rg) * K + ch * 8;

  auto stA = [&](int t, int h) {
    const long k0 = (long)t << 6;
#pragma unroll
    for (int i = 0; i < 2; ++i)
      gld16(Ap + (long)(h * 128 + i * 64) * K + k0,
            &Abuf[t & 1][(h * 128 + i * 64) * 64 + tid * 8]);
  };
  auto stB0 = [&](int t) {
    const long k0 = (long)t << 6;
#pragma unroll
    for (int i = 0; i < 2; ++i)
      gld16(Bp + (long)(i * 64) * K + k0, &Bbuf[t & 1][(i * 64) * 64 + tid * 8]);
  };
  auto stB1 = [&](int t) {
    const long k0 = (long)t << 6;
    gld16(Bp + (long)128 * K + k0, &Bbuf[t & 1][128 * 64 + tid * 8]);
  };

  const int nt = (int)(K >> 6);                  // 16
  stA(0, 0); stA(0, 1); stB0(0); stB1(0);
  stA(1, 0); stA(1, 1); stB0(1);
  WAITV(6);
  BAR;

  const int sl0 = (lh ^ (lr & 7)) * 8;
  const int sl1 = ((4 + lh) ^ (lr & 7)) * 8;

  for (int t = 0; t < nt; ++t) {
    const unsigned short* Ab = Abuf[t & 1];
    const unsigned short* Bb = Bbuf[t & 1];
    bh8 a0[4][2], a1[4][2], b0[2][2], b1[2];
    // phase 0: read A-half0 + B-half0, stage (t+1) B1
#pragma unroll
    for (int mi = 0; mi < 4; ++mi) {
      const int row = (2 * mi + wr) * 16 + lr;
      a0[mi][0] = *(const bh8*)&Ab[row * 64 + sl0];
      a0[mi][1] = *(const bh8*)&Ab[row * 64 + sl1];
    }
#pragma unroll
    for (int ni = 0; ni < 2; ++ni) {
      const int row = (4 * ni + wc) * 16 + lr;
      b0[ni][0] = *(const bh8*)&Bb[row * 64 + sl0];
      b0[ni][1] = *(const bh8*)&Bb[row * 64 + sl1];
    }
    if (t + 1 < nt) stB1(t + 1);
    LGKM8;
    BAR;
    LGKM0; SBAR0;
    __builtin_amdgcn_s_setprio(1);
#pragma unroll
    for (int mi = 0; mi < 4; ++mi)
#pragma unroll
      for (int ni = 0; ni < 2; ++ni) {
        acc[mi][ni] = mfma16(a0[mi][0], b0[ni][0], acc[mi][ni]);
        acc[mi][ni] = mfma16(a0[mi][1], b0[ni][1], acc[mi][ni]);
      }
    __builtin_amdgcn_s_setprio(0);
    BAR;
    // phase 1: read A-half1, stage (t+2) A0
#pragma unroll
    for (int mi = 0; mi < 4; ++mi) {
      const int row = (2 * (mi + 4) + wr) * 16 + lr;
      a1[mi][0] = *(const bh8*)&Ab[row * 64 + sl0];
      a1[mi][1] = *(const bh8*)&Ab[row * 64 + sl1];
    }
    if (t + 2 < nt) stA(t + 2, 0);
    BAR;
    LGKM0; SBAR0;
    __builtin_amdgcn_s_setprio(1);
#pragma unroll
    for (int mi = 0; mi < 4; ++mi)
#pragma unroll
      for (int ni = 0; ni < 2; ++ni) {
        acc[mi + 4][ni] = mfma16(a1[mi][0], b0[ni][0], acc[mi + 4][ni]);
        acc[mi + 4][ni] = mfma16(a1[mi][1], b0[ni][1], acc[mi + 4][ni]);
      }
    __builtin_amdgcn_s_setprio(0);
    BAR;
    // phase 2: read B-half1 (ni=2), stage (t+2) A1
    {
      const int row = (8 + wc) * 16 + lr;
      b1[0] = *(const bh8*)&Bb[row * 64 + sl0];
      b1[1] = *(const bh8*)&Bb[row * 64 + sl1];
    }
    if (t + 2 < nt) stA(t + 2, 1);
    BAR;
    LGKM0; SBAR0;
    __builtin_amdgcn_s_setprio(1);
#pragma unroll
    for (int mi = 0; mi < 4; ++mi) {
      acc[mi][2] = mfma16(a0[mi][0], b1[0], acc[mi][2]);
      acc[mi][2] = mfma16(a0[mi][1], b1[1], acc[mi][2]);
    }
    __builtin_amdgcn_s_setprio(0);
    BAR;
    // phase 3: no reads, stage (t+2) B0, boundary vmcnt
    if (t + 2 < nt) stB0(t + 2);
    BAR;
    SBAR0;
    __builtin_amdgcn_s_setprio(1);
#pragma unroll
    for (int mi = 0; mi < 4; ++mi) {
      acc[mi + 4][2] = mfma16(a1[mi][0], b1[0], acc[mi + 4][2]);
      acc[mi + 4][2] = mfma16(a1[mi][1], b1[1], acc[mi + 4][2]);
    }
    __builtin_amdgcn_s_setprio(0);
    if (t + 1 < nt) {
      if (t + 2 < nt) { WAITV(6); } else { WAITV(0); }
      BAR;
    }
  }

  // epilogue: per-frag branch on 16-aligned base column
#pragma unroll
  for (int mi = 0; mi < 8; ++mi)
#pragma unroll
    for (int ni = 0; ni < 3; ++ni) {
      const int colb = (int)col0 + (4 * ni + wc) * 16;
      const int col = colb + lr;
      float bb = bias[col];
      if (colb >= 2048) {       // V -> Vt[(b*16+h)*64+dh][t]
        int cc = col - 2048;
        long row = row0 + (2 * mi + wr) * 16 + lh4;
        int bi = (int)(row >> 10), tt = (int)(row & 1023);
        ushort4 o;
        o.x = f2b(acc[mi][ni][0] + bb);
        o.y = f2b(acc[mi][ni][1] + bb);
        o.z = f2b(acc[mi][ni][2] + bb);
        o.w = f2b(acc[mi][ni][3] + bb);
        *(ushort4*)&Vtout[((size_t)(bi * 16 + (cc >> 6)) * 64 + (cc & 63)) *
                              1024 + tt] = o;
      } else {
        const float qsc = (colb < 1024) ? (0.03125f * LOG2E) : 1.0f;
#pragma unroll
        for (int r = 0; r < 4; ++r) {
          long row = row0 + (2 * mi + wr) * 16 + lh4 + r;
          Cout[row * N + col] = f2b((acc[mi][ni][r] + bb) * qsc);
        }
      }
    }
}

// ------------------- fp8 8-phase 256x256 GEMM, BK=128 (FF1 / FF2)
// Inputs x16-scaled AND k-permuted -> b128 fragment reads (r16-verified).
template <bool PART>
__global__ __launch_bounds__(512, 1) void gemm256f8(
    const unsigned char* __restrict__ A, const unsigned char* __restrict__ Bt,
    const float* __restrict__ bias, void* __restrict__ Cout,
    long N, long Kloop, long lda, long ldb, int MT, int NT, int CM, int CN) {
  __shared__ unsigned char Abuf[2][256 * 128];   // 64KB
  __shared__ unsigned char Bbuf[2][256 * 128];   // 64KB
  const int tid = threadIdx.x, lane = tid & 63, w = tid >> 6;
  const int wr = w >> 2, wc = w & 3;
  const int lr = lane & 15, lh = lane >> 4, lh4 = lh * 4;

  const int x = (int)blockIdx.x & 7, j = (int)blockIdx.x >> 3;
  const int gM = MT / CM;
  const int rowT = (x % gM) * CM + (j % CM);
  const int c = (x / gM) * CN + (j / CM);
  const int colT = c % NT, ksl = c / NT;
  const long row0 = (long)rowT * 256, col0 = (long)colT * 256;
  const long kOff = (long)ksl * Kloop;

  f4v acc[8][4];
#pragma unroll
  for (int i = 0; i < 8; ++i)
#pragma unroll
    for (int jj = 0; jj < 4; ++jj) acc[i][jj] = f4v{0.f, 0.f, 0.f, 0.f};

  const int rg = tid >> 3, sIdx = tid & 7;
  const int ch = sIdx ^ (rg & 7);
  const unsigned char* Ap = A + (row0 + rg) * lda + kOff + ch * 16;
  const unsigned char* Bp = Bt + (col0 + rg) * ldb + kOff + ch * 16;

  auto stA = [&](int t, int h) {
    const long k0 = (long)t << 7;
#pragma unroll
    for (int i = 0; i < 2; ++i)
      gld16(Ap + (long)(h * 128 + i * 64) * lda + k0,
            &Abuf[t & 1][(h * 128 + i * 64) * 128 + tid * 16]);
  };
  auto stB = [&](int t, int h) {
    const long k0 = (long)t << 7;
#pragma unroll
    for (int i = 0; i < 2; ++i)
      gld16(Bp + (long)(h * 128 + i * 64) * ldb + k0,
            &Bbuf[t & 1][(h * 128 + i * 64) * 128 + tid * 16]);
  };

  const int nt = (int)(Kloop >> 7);              // 8 for K=1024
  stA(0, 0); stA(0, 1); stB(0, 0); stB(0, 1);
  stA(1, 0); stA(1, 1); stB(1, 0);
  WAITV(6);
  BAR;

  const int c0b = ((lh * 2) ^ (lr & 7)) * 16;
  const int c1b = ((lh * 2 + 1) ^ (lr & 7)) * 16;

  for (int t = 0; t < nt; ++t) {
    const unsigned char* Ab = Abuf[t & 1];
    const unsigned char* Bb = Bbuf[t & 1];
    long a0[4][4], a1[4][4], b0[2][4], b1[2][4];
    // phase 0: A-half0 + B-half0 (12 b128 reads), stage (t+1) B1
#pragma unroll
    for (int mi = 0; mi < 4; ++mi) {
      const unsigned char* rp = &Ab[((2 * mi + wr) * 16 + lr) * 128];
      lg2 q0 = *(const lg2*)&rp[c0b];
      lg2 q1 = *(const lg2*)&rp[c1b];
      a0[mi][0] = q0[0]; a0[mi][1] = q0[1]; a0[mi][2] = q1[0]; a0[mi][3] = q1[1];
    }
#pragma unroll
    for (int ni = 0; ni < 2; ++ni) {
      const unsigned char* rp = &Bb[((4 * ni + wc) * 16 + lr) * 128];
      lg2 q0 = *(const lg2*)&rp[c0b];
      lg2 q1 = *(const lg2*)&rp[c1b];
      b0[ni][0] = q0[0]; b0[ni][1] = q0[1]; b0[ni][2] = q1[0]; b0[ni][3] = q1[1];
    }
    if (t + 1 < nt) stB(t + 1, 1);
    LGKM8;
    BAR;
    LGKM0; SBAR0;
    __builtin_amdgcn_s_setprio(1);
#pragma unroll
    for (int ks = 0; ks < 4; ++ks)
#pragma unroll
      for (int mi = 0; mi < 4; ++mi)
#pragma unroll
        for (int ni = 0; ni < 2; ++ni)
          acc[mi][ni] = mfma8(a0[mi][ks], b0[ni][ks], acc[mi][ni]);
    __builtin_amdgcn_s_setprio(0);
    BAR;
    // phase 1: A-half1 (8 reads), stage (t+2) A0
#pragma unroll
    for (int mi = 0; mi < 4; ++mi) {
      const unsigned char* rp = &Ab[((2 * (mi + 4) + wr) * 16 + lr) * 128];
      lg2 q0 = *(const lg2*)&rp[c0b];
      lg2 q1 = *(const lg2*)&rp[c1b];
      a1[mi][0] = q0[0]; a1[mi][1] = q0[1]; a1[mi][2] = q1[0]; a1[mi][3] = q1[1];
    }
    if (t + 2 < nt) stA(t + 2, 0);
    BAR;
    LGKM0; SBAR0;
    __builtin_amdgcn_s_setprio(1);
#pragma unroll
    for (int ks = 0; ks < 4; ++ks)
#pragma unroll
      for (int mi = 0; mi < 4; ++mi)
#pragma unroll
        for (int ni = 0; ni < 2; ++ni)
          acc[mi + 4][ni] = mfma8(a1[mi][ks], b0[ni][ks], acc[mi + 4][ni]);
    __builtin_amdgcn_s_setprio(0);
    BAR;
    // phase 2: B-half1 (4 reads), stage (t+2) A1
#pragma unroll
    for (int ni = 0; ni < 2; ++ni) {
      const unsigned char* rp = &Bb[((4 * (ni + 2) + wc) * 16 + lr) * 128];
      lg2 q0 = *(const lg2*)&rp[c0b];
      lg2 q1 = *(const lg2*)&rp[c1b];
      b1[ni][0] = q0[0]; b1[ni][1] = q0[1]; b1[ni][2] = q1[0]; b1[ni][3] = q1[1];
    }
    if (t + 2 < nt) stA(t + 2, 1);
    BAR;
    LGKM0; SBAR0;
    __builtin_amdgcn_s_setprio(1);
#pragma unroll
    for (int ks = 0; ks < 4; ++ks)
#pragma unroll
      for (int mi = 0; mi < 4; ++mi)
#pragma unroll
        for (int ni = 0; ni < 2; ++ni)
          acc[mi][ni + 2] = mfma8(a0[mi][ks], b1[ni][ks], acc[mi][ni + 2]);
    __builtin_amdgcn_s_setprio(0);
    BAR;
    // phase 3: no reads, stage (t+2) B0, boundary vmcnt
    if (t + 2 < nt) stB(t + 2, 0);
    BAR;
    SBAR0;
    __builtin_amdgcn_s_setprio(1);
#pragma unroll
    for (int ks = 0; ks < 4; ++ks)
#pragma unroll
      for (int mi = 0; mi < 4; ++mi)
#pragma unroll
        for (int ni = 0; ni < 2; ++ni)
          acc[mi + 4][ni + 2] = mfma8(a1[mi][ks], b1[ni][ks], acc[mi + 4][ni + 2]);
    __builtin_amdgcn_s_setprio(0);
    if (t + 1 < nt) {
      if (t + 2 < nt) { WAITV(6); } else { WAITV(0); }
      BAR;
    }
  }

  constexpr float DS = 1.f / 256.f;
  if (PART) {   // FF2: bf16 partial plane (bias added in ln2_fuse), N linear
    unsigned short* P = (unsigned short*)Cout + (size_t)ksl * 4096 * 1024;
#pragma unroll
    for (int mi = 0; mi < 8; ++mi)
#pragma unroll
      for (int ni = 0; ni < 4; ++ni) {
        long col = col0 + (4 * ni + wc) * 16 + lr;
#pragma unroll
        for (int r = 0; r < 4; ++r) {
          long row = row0 + (2 * mi + wr) * 16 + lh4 + r;
          P[row * N + col] = f2b(acc[mi][ni][r] * DS);
        }
      }
    return;
  }
  // FF1: relu(acc/256 + b1) -> e4m3(v*16) at k-PERMUTED column (feeds FF2)
#pragma unroll
  for (int mi = 0; mi < 8; ++mi)
#pragma unroll
    for (int ni = 0; ni < 4; ++ni) {
      const int col = (int)col0 + (4 * ni + wc) * 16 + lr;
      float bb = bias[col];
      const int colp = perm128(col);
#pragma unroll
      for (int r = 0; r < 4; ++r) {
        long row = row0 + (2 * mi + wr) * 16 + lh4 + r;
        float v = fmaxf(acc[mi][ni][r] * DS + bb, 0.f);
        ((unsigned char*)Cout)[row * N + colp] = f2e4m3(v * 16.f);
      }
    }
}

// ------------------------------------------- small GEMM (logits), round-5 form
template <int TM, int TN, bool RELU, bool F32OUT>
__global__ __launch_bounds__(256) void gemm4(
    const unsigned short* __restrict__ A, const unsigned short* __restrict__ Bt,
    const float* __restrict__ bias, void* __restrict__ Cout, long N, long K) {
  constexpr int MI = TM / 32, NI = TN / 32;
  constexpr int ABUF = TM * 64, BBUF = TN * 64;
  __shared__ unsigned short As[2 * ABUF];
  __shared__ unsigned short Bs[2 * BBUF];
  const int tid = threadIdx.x;
  const int lane = tid & 63, w = tid >> 6;
  const int wr = w >> 1, wc = w & 1;
  const int lr = lane & 15, lh = lane >> 4, lh4 = lh * 4;
  const long row0 = (long)blockIdx.x * TM, col0 = (long)blockIdx.y * TN;
  f4v acc[MI][NI];
#pragma unroll
  for (int i = 0; i < MI; ++i)
#pragma unroll
    for (int j = 0; j < NI; ++j) acc[i][j] = f4v{0.f, 0.f, 0.f, 0.f};
  const int rg = tid >> 3, s = tid & 7;
  const int ch = s ^ (rg & 7);
  const unsigned short* Ap = A + (row0 + rg) * K + ch * 8;
  const unsigned short* Bp = Bt + (col0 + rg) * K + ch * 8;
  auto stage = [&](int t, int buf) {
    const long k0 = (long)t << 6;
#pragma unroll
    for (int i = 0; i < MI; ++i)
      gld16(Ap + i * 32 * K + k0, &As[buf * ABUF + (i * 256 + tid) * 8]);
#pragma unroll
    for (int i = 0; i < NI; ++i)
      gld16(Bp + i * 32 * K + k0, &Bs[buf * BBUF + (i * 256 + tid) * 8]);
  };
  const int nt = (int)(K >> 6);
  stage(0, 0);
  for (int t = 0; t < nt; ++t) {
    const int cur = t & 1;
    if (t + 1 < nt) {
      stage(t + 1, cur ^ 1);
      WAITV(6);
    } else {
      WAITV(0);
    }
    BAR;
    const unsigned short* Ab = &As[cur * ABUF];
    const unsigned short* Bb = &Bs[cur * BBUF];
#pragma unroll
    for (int ks = 0; ks < 2; ++ks) {
      bh8 a[MI], b[NI];
      const int slot = ((ks << 2) | lh) ^ (lr & 7);
#pragma unroll
      for (int mi = 0; mi < MI; ++mi) {
        int m = wr * (TM / 2) + mi * 16 + lr;
        a[mi] = *(const bh8*)((const char*)Ab + m * 128 + slot * 16);
      }
#pragma unroll
      for (int ni = 0; ni < NI; ++ni) {
        int n = wc * (TN / 2) + ni * 16 + lr;
        b[ni] = *(const bh8*)((const char*)Bb + n * 128 + slot * 16);
      }
#pragma unroll
      for (int mi = 0; mi < MI; ++mi)
#pragma unroll
        for (int ni = 0; ni < NI; ++ni)
          acc[mi][ni] = mfma16(a[mi], b[ni], acc[mi][ni]);
    }
    BAR;
  }
#pragma unroll
  for (int mi = 0; mi < MI; ++mi) {
#pragma unroll
    for (int ni = 0; ni < NI; ++ni) {
      long col = col0 + wc * (TN / 2) + ni * 16 + lr;
      float bb = bias[col];
#pragma unroll
      for (int r = 0; r < 4; ++r) {
        long row = row0 + wr * (TM / 2) + mi * 16 + lh4 + r;
        float v = acc[mi][ni][r] + bb;
        if (RELU) v = fmaxf(v, 0.f);
        if (F32OUT) ((float*)Cout)[row * N + col] = v;
        else ((unsigned short*)Cout)[row * N + col] = f2b(v);
      }
    }
  }
}

// ------------------------------------------------- flash attention (MFMA)
// QBLK=128 x KVBLK=128, 8 waves; scores pre-scaled into exp2 domain
// (Q epilogue carries log2e/32) -> raw exp2f, threshold 8*log2e.
__global__ __launch_bounds__(512) void attn_mfma(
    const unsigned short* __restrict__ QKV, const unsigned short* __restrict__ Vt,
    unsigned short* __restrict__ Hout) {
  __shared__ unsigned short Ks[2][128 * 64];   // [key][dh] swizzled, 32KB
  __shared__ unsigned short Vs[2][2][64 * 64]; // [half][dh][key] swizzled, 32KB
  __shared__ unsigned short Ps[8][16 * 64];    // per-wave [q][key-half], 16KB
  const int tid = threadIdx.x, w = tid >> 6, lane = tid & 63;
  const int wid = ((int)blockIdx.x & 7) * 64 + ((int)blockIdx.x >> 3);
  const int bh = wid >> 3;                     // 8 consecutive bh per XCD
  const int qt = 7 - (wid & 7);                // heavy q-blocks first
  const int b = bh >> 4, h = bh & 15;
  const int lr = lane & 15, lh = lane >> 4, lh4 = lh * 4;

  const unsigned short* qp =
      QKV + (size_t)(b * 1024 + qt * 128 + w * 16 + lr) * 3072 + h * 64 + lh * 8;
  bh8 aq0 = *(const bh8*)qp;
  bh8 aq1 = *(const bh8*)(qp + 32);

  f4v o[4];
#pragma unroll
  for (int i = 0; i < 4; ++i) o[i] = f4v{0.f, 0.f, 0.f, 0.f};
  float m = -1e30f, l = 0.f;

  const int r8 = tid >> 3, slot = tid & 7;     // r8 0..63
  unsigned short* pw = &Ps[w][0];

  auto stage = [&](int kt, int buf) {
    int c8 = (slot ^ (r8 & 7)) * 8;
    gld16(QKV + (size_t)(b * 1024 + kt * 128 + r8) * 3072 + 1024 + h * 64 + c8,
          &Ks[buf][tid * 8]);
    int r2 = r8 + 64;
    int c82 = (slot ^ (r2 & 7)) * 8;
    gld16(QKV + (size_t)(b * 1024 + kt * 128 + r2) * 3072 + 1024 + h * 64 + c82,
          &Ks[buf][64 * 64 + tid * 8]);
    gld16(Vt + (size_t)(bh * 64 + r8) * 1024 + kt * 128 + c8, &Vs[buf][0][tid * 8]);
    gld16(Vt + (size_t)(bh * 64 + r8) * 1024 + kt * 128 + 64 + c8,
          &Vs[buf][1][tid * 8]);
  };

  stage(0, 0);

  for (int kt = 0; kt <= qt; ++kt) {
    const int cur = kt & 1;
    if (kt < qt) {
      stage(kt + 1, cur ^ 1);
      WAITV(4);
    } else {
      WAITV(0);
    }
    BAR;

    f4v s[8];
#pragma unroll
    for (int nt = 0; nt < 8; ++nt) {
      bh8 k0 = lds_swz(Ks[cur], nt * 16 + lr, lh * 16);
      bh8 k1 = lds_swz(Ks[cur], nt * 16 + lr, lh * 16 + 64);
      f4v z = f4v{0.f, 0.f, 0.f, 0.f};
      z = mfma16(k0, aq0, z);
      z = mfma16(k1, aq1, z);
      s[nt] = z;
    }
    if (kt == qt) {
      const int qloc = w * 16 + lr;
#pragma unroll
      for (int nt = 0; nt < 8; ++nt)
#pragma unroll
        for (int r = 0; r < 4; ++r)
          if ((nt * 16 + lh4 + r) > qloc) s[nt][r] = -1e30f;
    }
    float tm = s[0][0];
#pragma unroll
    for (int nt = 0; nt < 8; ++nt)
#pragma unroll
      for (int r = 0; r < 4; ++r) tm = fmaxf(tm, s[nt][r]);
    tm = fmaxf(tm, __shfl_xor(tm, 16));
    tm = fmaxf(tm, __shfl_xor(tm, 32));

    const bool resc = __any(tm > m + 8.f * LOG2E);   // defer-max, log2 domain
    const float mu = resc ? fmaxf(m, tm) : m;
    float sum = 0.f;
#pragma unroll
    for (int nt = 0; nt < 8; ++nt)
#pragma unroll
      for (int r = 0; r < 4; ++r) {
        float e = exp2f(s[nt][r] - mu);
        s[nt][r] = e;
        sum += e;
      }
    sum += __shfl_xor(sum, 16);
    sum += __shfl_xor(sum, 32);
    if (resc) {
      float corr = exp2f(m - mu);
      m = mu;
      l = l * corr + sum;
      float c0 = __shfl(corr, lh4 + 0), c1 = __shfl(corr, lh4 + 1);
      float c2 = __shfl(corr, lh4 + 2), c3 = __shfl(corr, lh4 + 3);
#pragma unroll
      for (int nt = 0; nt < 4; ++nt) {
        o[nt][0] *= c0; o[nt][1] *= c1; o[nt][2] *= c2; o[nt][3] *= c3;
      }
    } else {
      l += sum;
    }
#pragma unroll
    for (int hh = 0; hh < 2; ++hh) {
#pragma unroll
      for (int q = 0; q < 4; ++q) {
        const int nt = hh * 4 + q;
        unsigned int u0, u1;
        asm("v_cvt_pk_bf16_f32 %0, %1, %2" : "=v"(u0) : "v"(s[nt][0]), "v"(s[nt][1]));
        asm("v_cvt_pk_bf16_f32 %0, %1, %2" : "=v"(u1) : "v"(s[nt][2]), "v"(s[nt][3]));
        uint2 pk{u0, u1};
        *(uint2*)((char*)pw + lr * 128 + ((q * 32 + lh * 8) ^ ((lr & 7) << 4))) = pk;
      }
      bh8 pa0 = lds_swz(pw, lr, lh * 16);
      bh8 pa1 = lds_swz(pw, lr, lh * 16 + 64);
      const unsigned short* Vh = Vs[cur][hh];
#pragma unroll
      for (int nt2 = 0; nt2 < 4; ++nt2) {
        bh8 v0 = lds_swz(Vh, nt2 * 16 + lr, lh * 16);
        bh8 v1 = lds_swz(Vh, nt2 * 16 + lr, lh * 16 + 64);
        o[nt2] = mfma16(pa0, v0, o[nt2]);
        o[nt2] = mfma16(pa1, v1, o[nt2]);
      }
    }
    BAR;
  }
  float linv = 1.f / l;
  float l0 = __shfl(linv, lh4 + 0), l1 = __shfl(linv, lh4 + 1);
  float l2 = __shfl(linv, lh4 + 2), l3 = __shfl(linv, lh4 + 3);
  const size_t rowb = (size_t)(b * 1024 + qt * 128 + w * 16);
#pragma unroll
  for (int nt = 0; nt < 4; ++nt) {
    int col = h * 64 + nt * 16 + lr;
    Hout[(rowb + lh4 + 0) * 1024 + col] = f2b(o[nt][0] * l0);
    Hout[(rowb + lh4 + 1) * 1024 + col] = f2b(o[nt][1] * l1);
    Hout[(rowb + lh4 + 2) * 1024 + col] = f2b(o[nt][2] * l2);
    Hout[(rowb + lh4 + 3) * 1024 + col] = f2b(o[nt][3] * l3);
  }
}

// ----------------- y = x + layer_norm(x); FP8: emit e4m3(y*16) k-PERMUTED
template <bool FP8>
__global__ __launch_bounds__(256) void ln_res_bf(
    const unsigned short* __restrict__ Xi, const float* __restrict__ wln,
    void* __restrict__ Y) {
  int row = blockIdx.x, tid = threadIdx.x;
  ushort4 u = ((const ushort4*)(Xi + (size_t)row * 1024))[tid];
  float x0 = b2f(u.x), x1 = b2f(u.y), x2 = b2f(u.z), x3 = b2f(u.w);
  float s = x0 + x1 + x2 + x3;
  float ss = x0 * x0 + x1 * x1 + x2 * x2 + x3 * x3;
#pragma unroll
  for (int off = 32; off; off >>= 1) {
    s += __shfl_xor(s, off);
    ss += __shfl_xor(ss, off);
  }
  __shared__ float sw[4], ssw[4];
  int wv = tid >> 6, ln = tid & 63;
  if (ln == 0) { sw[wv] = s; ssw[wv] = ss; }
  __syncthreads();
  s = sw[0] + sw[1] + sw[2] + sw[3];
  ss = ssw[0] + ssw[1] + ssw[2] + ssw[3];
  float mean = s * (1.f / 1024.f);
  float var = ss * (1.f / 1024.f) - mean * mean;
  float rstd = rsqrtf(var + 1e-5f);
  float4 wv4 = ((const float4*)wln)[tid];
  float y0 = x0 + (x0 - mean) * rstd * wv4.x;
  float y1 = x1 + (x1 - mean) * rstd * wv4.y;
  float y2 = x2 + (x2 - mean) * rstd * wv4.z;
  float y3 = x3 + (x3 - mean) * rstd * wv4.w;
  if (FP8) {
    *(unsigned int*)((unsigned char*)Y + (size_t)row * 1024 + perm128(tid * 4)) =
        pk4_e4m3(y0 * 16.f, y1 * 16.f, y2 * 16.f, y3 * 16.f);
  } else {
    ushort4 out;
    out.x = f2b(y0); out.y = f2b(y1); out.z = f2b(y2); out.w = f2b(y3);
    ((ushort4*)Y)[row * 256 + tid] = out;
  }
}

// ---------------- FF2 split-K reduce + bias + (x + layer_norm(x)) fused
__global__ __launch_bounds__(256) void ln2_fuse(
    const unsigned short* __restrict__ P, const float* __restrict__ b2,
    const float* __restrict__ wln, unsigned short* __restrict__ Y) {
  int row = blockIdx.x, tid = threadIdx.x;
  const size_t plane = (size_t)4096 * 1024;
  float x0 = 0.f, x1 = 0.f, x2 = 0.f, x3 = 0.f;
#pragma unroll
  for (int pl = 0; pl < 4; ++pl) {
    ushort4 u = *(const ushort4*)&P[pl * plane + (size_t)row * 1024 + tid * 4];
    x0 += b2f(u.x); x1 += b2f(u.y); x2 += b2f(u.z); x3 += b2f(u.w);
  }
  float4 bb = ((const float4*)b2)[tid];
  x0 += bb.x; x1 += bb.y; x2 += bb.z; x3 += bb.w;
  float s = x0 + x1 + x2 + x3;
  float ss = x0 * x0 + x1 * x1 + x2 * x2 + x3 * x3;
#pragma unroll
  for (int off = 32; off; off >>= 1) {
    s += __shfl_xor(s, off);
    ss += __shfl_xor(ss, off);
  }
  __shared__ float sw[4], ssw[4];
  int wv = tid >> 6, ln = tid & 63;
  if (ln == 0) { sw[wv] = s; ssw[wv] = ss; }
  __syncthreads();
  s = sw[0] + sw[1] + sw[2] + sw[3];
  ss = ssw[0] + ssw[1] + ssw[2] + ssw[3];
  float mean = s * (1.f / 1024.f);
  float var = ss * (1.f / 1024.f) - mean * mean;
  float rstd = rsqrtf(var + 1e-5f);
  float4 wv4 = ((const float4*)wln)[tid];
  ushort4 out;
  out.x = f2b(x0 + (x0 - mean) * rstd * wv4.x);
  out.y = f2b(x1 + (x1 - mean) * rstd * wv4.y);
  out.z = f2b(x2 + (x2 - mean) * rstd * wv4.z);
  out.w = f2b(x3 + (x3 - mean) * rstd * wv4.w);
  ((ushort4*)(Y + (size_t)row * 1024))[tid] = out;
}

// ------------------------------------------- probs = softmax over T axis
__global__ __launch_bounds__(256) void softmaxT_kernel(
    const float* __restrict__ logits, float* __restrict__ probs) {
  int b = blockIdx.x / VOC;
  int v = blockIdx.x - b * VOC;
  const float* src = logits + (size_t)b * 1024 * 128 + v;
  float vals[4];
  float m = -1e30f;
#pragma unroll
  for (int i = 0; i < 4; ++i) {
    int t = threadIdx.x + 256 * i;
    vals[i] = src[(size_t)t * 128];
    m = fmaxf(m, vals[i]);
  }
#pragma unroll
  for (int off = 32; off; off >>= 1) m = fmaxf(m, __shfl_xor(m, off));
  __shared__ float sm[4], ssum[4];
  int wv = threadIdx.x >> 6, ln = threadIdx.x & 63;
  if (ln == 0) sm[wv] = m;
  __syncthreads();
  m = fmaxf(fmaxf(sm[0], sm[1]), fmaxf(sm[2], sm[3]));
  float s = 0.f;
#pragma unroll
  for (int i = 0; i < 4; ++i) { vals[i] = __expf(vals[i] - m); s += vals[i]; }
#pragma unroll
  for (int off = 32; off; off >>= 1) s += __shfl_xor(s, off);
  if (ln == 0) ssum[wv] = s;
  __syncthreads();
  s = ssum[0] + ssum[1] + ssum[2] + ssum[3];
  float inv = 1.f / s;
  float* dst = probs + (size_t)b * 1024 * VOC + v;
#pragma unroll
  for (int i = 0; i < 4; ++i) {
    int t = threadIdx.x + 256 * i;
    dst[(size_t)t * VOC] = vals[i] * inv;
  }
}

// ------------------------- per-row -log_softmax_V(probs)[target] partials
__global__ __launch_bounds__(256) void loss_rows_kernel(
    const float* __restrict__ probs, const int* __restrict__ tgt,
    float* __restrict__ partial) {
  int wv = threadIdx.x >> 6, lane = threadIdx.x & 63;
  int row = blockIdx.x * 4 + wv;
  const float* p = probs + (size_t)row * VOC;
  float x0 = p[lane];
  float x1 = (lane == 0) ? p[64] : -1e30f;
  float m = fmaxf(x0, x1);
#pragma unroll
  for (int off = 32; off; off >>= 1) m = fmaxf(m, __shfl_xor(m, off));
  float s = __expf(x0 - m) + ((lane == 0) ? __expf(x1 - m) : 0.f);
#pragma unroll
  for (int off = 32; off; off >>= 1) s += __shfl_xor(s, off);
  if (lane == 0) {
    int tg = tgt[row];
    partial[row] = (p[tg] - m) - logf(s);
  }
}

__global__ __launch_bounds__(256) void loss_final_kernel(
    const float* __restrict__ partial, float* __restrict__ out) {
  float s = 0.f;
  for (int i = threadIdx.x; i < Mrow; i += 256) s += partial[i];
#pragma unroll
  for (int off = 32; off; off >>= 1) s += __shfl_xor(s, off);
  __shared__ float sw[4];
  int wv = threadIdx.x >> 6, ln = threadIdx.x & 63;
  if (ln == 0) sw[wv] = s;
  __syncthreads();
  if (threadIdx.x == 0) out[0] = -(sw[0] + sw[1] + sw[2] + sw[3]) / (float)Mrow;
}

// ------------------------------------------------------------------ launch
extern "C" void kernel_launch(void* const* d_in, const int* in_sizes, int n_in,
                              void* d_out, int out_size, void* d_ws,
                              size_t ws_size, hipStream_t stream) {
  (void)in_sizes; (void)n_in; (void)out_size; (void)ws_size;
  const int*   tok    = (const int*)d_in[0];
  const int*   target = (const int*)d_in[1];
  const float* Wtok   = (const float*)d_in[3];
  const float* Wpos   = (const float*)d_in[4];
  const float* Wq = (const float*)d_in[5];  const float* bq = (const float*)d_in[6];
  const float* Wk = (const float*)d_in[7];  const float* bk = (const float*)d_in[8];
  const float* Wv = (const float*)d_in[9];  const float* bv = (const float*)d_in[10];
  const float* W1 = (const float*)d_in[11]; const float* b1 = (const float*)d_in[12];
  const float* W2 = (const float*)d_in[13]; const float* b2 = (const float*)d_in[14];
  const float* lnw = (const float*)d_in[15];
  const float* Wf = (const float*)d_in[16]; const float* bf = (const float*)d_in[17];
  float* out = (float*)d_out;

  char* p = (char*)d_ws;
  unsigned short* Xb    = (unsigned short*)p; p += (size_t)Mrow * 1024 * 2;
  unsigned short* QKVb  = (unsigned short*)p; p += (size_t)Mrow * 3072 * 2;
  unsigned short* Vt    = (unsigned short*)p; p += (size_t)64 * 64 * 1024 * 2;
  unsigned short* Hb    = (unsigned short*)p; p += (size_t)Mrow * 1024 * 2;
  unsigned char*  F2b8  = (unsigned char*)p;  p += (size_t)Mrow * 1024;
  unsigned char*  FF1b8 = (unsigned char*)p;  p += (size_t)Mrow * 4096;
  unsigned short* WqkvT = (unsigned short*)p; p += (size_t)3072 * 1024 * 2;
  unsigned char*  W1T8  = (unsigned char*)p;  p += (size_t)4096 * 1024;
  unsigned char*  W2T8  = (unsigned char*)p;  p += (size_t)1024 * 4096;
  unsigned short* WfT   = (unsigned short*)p; p += (size_t)128 * 1024 * 2;
  float* bqkv = (float*)p; p += 3072 * 4;
  float* bfp  = (float*)p; p += 128 * 4;
  float* LOG  = (float*)p; p += (size_t)Mrow * 128 * 4;
  float* PART = (float*)p; p += Mrow * 4;
  // FF2 split-K bf16 partials: alias dead-at-FF2-time QKVb+Vt (32 MB)
  unsigned short* Pff2 = QKVb;

  // one dispatch: all weight conversions + bias packing
  prep_all<<<11405, 256, 0, stream>>>(Wq, Wk, Wv, W1, W2, Wf, bq, bk, bv, bf,
                                      WqkvT, W1T8, W2T8, WfT, bqkv, bfp);
  embed_bf<<<Mrow, 256, 0, stream>>>(tok, Wtok, Wpos, Xb);

  for (int l = 0; l < NL; ++l) {
    // QKV bf16: 256x192 8-phase, grid 256 = 1 block/CU EXACT (chunk 4x8)
    gemm192<<<256, 512, 0, stream>>>(
        Xb, WqkvT, bqkv, QKVb, Vt, 3072, 1024, 16, 4, 8);
    // attention: QBLK=128, KVBLK=128, 8 waves, 512 blocks (2 blk/CU)
    attn_mfma<<<512, 512, 0, stream>>>(QKVb, Vt, Hb);
    ln_res_bf<true><<<Mrow, 256, 0, stream>>>(Hb, lnw, F2b8);     // h+ln(h), fp8p
    // FF1 fp8 (b128 frags): grid 256; out fp8 k-permuted for FF2
    gemm256f8<false><<<256, 512, 0, stream>>>(
        F2b8, W1T8, b1, FF1b8, 4096, 1024, 1024, 1024, 16, 16, 4, 8);
    // FF2 fp8: split-K4 (Kloop=1024), grid 256, bf16 partials
    gemm256f8<true><<<256, 512, 0, stream>>>(
        FF1b8, W2T8, nullptr, Pff2, 1024, 1024, 4096, 4096, 16, 4, 4, 8);
    ln2_fuse<<<Mrow, 256, 0, stream>>>(Pff2, b2, lnw, Xb);        // ff + ln(ff)
  }

  gemm4<64, 128, false, true><<<dim3(64, 1), 256, 0, stream>>>(
      Xb, WfT, bfp, LOG, 128, 1024);                              // logits (f32)
  softmaxT_kernel<<<4 * VOC, 256, 0, stream>>>(LOG, out + 1);
  loss_rows_kernel<<<Mrow / 4, 256, 0, stream>>>(out + 1, target, PART);
  loss_final_kernel<<<1, 256, 0, stream>>>(PART, out);
}

// Round 18
// 904.594 us; speedup vs baseline: 1.0278x; 1.0278x over previous
//
#include <hip/hip_runtime.h>

typedef __attribute__((ext_vector_type(8))) short bh8;    // 8 bf16 = 4 VGPR
typedef __attribute__((ext_vector_type(4))) float f4v;    // 16x16 MFMA acc
typedef __attribute__((ext_vector_type(2))) long lg2;     // 16B fp8 frag pair

constexpr int VOC = 65;
constexpr int NL  = 6;
constexpr int Mrow = 4096;   // B*T

__device__ inline float b2f(unsigned short u) {
  union { unsigned int i; float f; } x; x.i = ((unsigned int)u) << 16; return x.f;
}
__device__ inline unsigned short f2b(float f) {
  union { float f; unsigned int i; } x; x.f = f;
  return (unsigned short)((x.i + 0x7FFFu + ((x.i >> 16) & 1u)) >> 16);
}
__device__ inline unsigned char f2e4m3(float v) {
  return (unsigned char)(__builtin_amdgcn_cvt_pk_fp8_f32(v, v, 0, false) & 0xFF);
}
__device__ inline unsigned int pk4_e4m3(float a, float b, float c, float d) {
  int v = __builtin_amdgcn_cvt_pk_fp8_f32(a, b, 0, false);
  v = __builtin_amdgcn_cvt_pk_fp8_f32(c, d, v, true);
  return (unsigned int)v;
}
// k-permutation within each 128-block: [ks(2)|lh(2)|b(3)] -> [lh|ks|b].
// Applied identically to BOTH fp8 operands at production time; MFMA then
// consumes the correct original k at every logical position. Involution.
__device__ inline int perm128(int k) {
  return (k & ~127) | (k & 7) | (((k >> 5) & 3) << 3) | (((k >> 3) & 3) << 5);
}
__device__ inline void gld16(const void* g, void* l) {
  __builtin_amdgcn_global_load_lds(
      (const __attribute__((address_space(1))) unsigned int*)g,
      (__attribute__((address_space(3))) unsigned int*)l, 16, 0, 0);
}
// swizzled LDS b128 read from a row-major [rows][64 bf16] tile (128 B rows)
__device__ inline bh8 lds_swz(const unsigned short* base, int row, int colbyte) {
  int off = row * 128 + (colbyte ^ ((row & 7) << 4));
  return *(const bh8*)((const char*)base + off);
}
__device__ inline f4v mfma16(bh8 a, bh8 b, f4v c) {
  return __builtin_amdgcn_mfma_f32_16x16x32_bf16(a, b, c, 0, 0, 0);
}
__device__ inline f4v mfma8(long a, long b, f4v c) {
  return __builtin_amdgcn_mfma_f32_16x16x32_fp8_fp8(a, b, c, 0, 0, 0);
}
#define WAITV(n) asm volatile("s_waitcnt vmcnt(" #n ")" ::: "memory")
#define LGKM0 asm volatile("s_waitcnt lgkmcnt(0)" ::: "memory")
#define LGKM8 asm volatile("s_waitcnt lgkmcnt(8)" ::: "memory")
#define SBAR0 __builtin_amdgcn_sched_barrier(0)
#define BAR __builtin_amdgcn_s_barrier()

// ---------------------------------------------------------------- weight prep
__global__ __launch_bounds__(256) void wt_conv(const float* __restrict__ src,
    unsigned short* __restrict__ dst, int K, int N) {
  __shared__ float t[32][33];
  int k0 = blockIdx.x * 32, n0 = blockIdx.y * 32;
  int tid = threadIdx.x;
#pragma unroll
  for (int i = 0; i < 4; ++i) {
    int idx = tid + i * 256;
    int kr = idx >> 5, nc = idx & 31;
    t[kr][nc] = (n0 + nc < N) ? src[(size_t)(k0 + kr) * N + n0 + nc] : 0.f;
  }
  __syncthreads();
#pragma unroll
  for (int i = 0; i < 4; ++i) {
    int idx = tid + i * 256;
    int nr = idx >> 5, kc = idx & 31;
    dst[(size_t)(n0 + nr) * K + k0 + kc] = f2b(t[kc][nr]);
  }
}

// fp8 weights, pre-scaled x16, K-PERMUTED: dst[n][perm(k)] = e4m3(src[k][n]*16)
__global__ __launch_bounds__(256) void wt_conv8(const float* __restrict__ src,
    unsigned char* __restrict__ dst, int K, int N) {
  __shared__ float t[32][33];
  int k0 = blockIdx.x * 32, n0 = blockIdx.y * 32;
  int tid = threadIdx.x;
#pragma unroll
  for (int i = 0; i < 4; ++i) {
    int idx = tid + i * 256;
    int kr = idx >> 5, nc = idx & 31;
    t[kr][nc] = (n0 + nc < N) ? src[(size_t)(k0 + kr) * N + n0 + nc] : 0.f;
  }
  __syncthreads();
#pragma unroll
  for (int i = 0; i < 4; ++i) {
    int idx = tid + i * 256;
    int nr = idx >> 5, kc = idx & 31;
    dst[(size_t)(n0 + nr) * K + perm128(k0 + kc)] = f2e4m3(t[kc][nr] * 16.f);
  }
}

__global__ __launch_bounds__(256) void bias_prep(
    const float* __restrict__ bq, const float* __restrict__ bk,
    const float* __restrict__ bv, const float* __restrict__ bf,
    float* __restrict__ bqkv, float* __restrict__ bfp) {
  int i = blockIdx.x * 256 + threadIdx.x;
  if (i < 1024) bqkv[i] = bq[i];
  else if (i < 2048) bqkv[i] = bk[i - 1024];
  else if (i < 3072) bqkv[i] = bv[i - 2048];
  else if (i < 3200) bfp[i - 3072] = (i - 3072 < VOC) ? bf[i - 3072] : 0.f;
}

// ---------------------------------------------------------------- embedding
__global__ __launch_bounds__(256) void embed_bf(const int* __restrict__ tok,
    const float* __restrict__ Wtok, const float* __restrict__ Wpos,
    unsigned short* __restrict__ Xb) {
  int bt = blockIdx.x, t = bt & 1023, tid = threadIdx.x;
  int id = tok[bt];
  float4 a = ((const float4*)(Wtok + (size_t)id * 1024))[tid];
  float4 p = ((const float4*)(Wpos + (size_t)t * 1024))[tid];
  ushort4 o;
  o.x = f2b(a.x + p.x); o.y = f2b(a.y + p.y);
  o.z = f2b(a.z + p.z); o.w = f2b(a.w + p.w);
  ((ushort4*)(Xb + (size_t)bt * 1024))[tid] = o;
}

// ---------------------- QKV GEMM: 256x192 tile, 8-phase bf16, grid 256 EXACT
__global__ __launch_bounds__(512, 1) void gemm192(
    const unsigned short* __restrict__ A, const unsigned short* __restrict__ Bt,
    const float* __restrict__ bias, unsigned short* __restrict__ Cout,
    unsigned short* __restrict__ Vtout, long N, long K,
    int MT, int CM, int CN) {
  __shared__ unsigned short Abuf[2][256 * 64];   // 64KB
  __shared__ unsigned short Bbuf[2][192 * 64];   // 48KB
  const int tid = threadIdx.x, lane = tid & 63, w = tid >> 6;
  const int wr = w >> 2, wc = w & 3;             // 2M x 4N waves
  const int lr = lane & 15, lh = lane >> 4, lh4 = lh * 4;

  const int x = (int)blockIdx.x & 7, j = (int)blockIdx.x >> 3;
  const int gM = MT / CM;
  const int rowT = (x % gM) * CM + (j % CM);
  const int colT = (x / gM) * CN + (j / CM);
  const long row0 = (long)rowT * 256, col0 = (long)colT * 192;

  f4v acc[8][3];
#pragma unroll
  for (int i = 0; i < 8; ++i)
#pragma unroll
    for (int jj = 0; jj < 3; ++jj) acc[i][jj] = f4v{0.f, 0.f, 0.f, 0.f};

  const int rg = tid >> 3, sIdx = tid & 7;
  const int ch = sIdx ^ (rg & 7);
  const unsigned short* Ap = A + (row0 + rg) * K + ch * 8;
  const unsigned short* Bp = Bt + (col0 + rg) * K + ch * 8;

  auto stA = [&](int t, int h) {
    const long k0 = (long)t << 6;
#pragma unroll
    for (int i = 0; i < 2; ++i)
      gld16(Ap + (long)(h * 128 + i * 64) * K + k0,
            &Abuf[t & 1][(h * 128 + i * 64) * 64 + tid * 8]);
  };
  auto stB0 = [&](int t) {
    const long k0 = (long)t << 6;
#pragma unroll
    for (int i = 0; i < 2; ++i)
      gld16(Bp + (long)(i * 64) * K + k0, &Bbuf[t & 1][(i * 64) * 64 + tid * 8]);
  };
  auto stB1 = [&](int t) {
    const long k0 = (long)t << 6;
    gld16(Bp + (long)128 * K + k0, &Bbuf[t & 1][128 * 64 + tid * 8]);
  };

  const int nt = (int)(K >> 6);                  // 16
  stA(0, 0); stA(0, 1); stB0(0); stB1(0);
  stA(1, 0); stA(1, 1); stB0(1);
  WAITV(6);
  BAR;

  const int sl0 = (lh ^ (lr & 7)) * 8;
  const int sl1 = ((4 + lh) ^ (lr & 7)) * 8;

  for (int t = 0; t < nt; ++t) {
    const unsigned short* Ab = Abuf[t & 1];
    const unsigned short* Bb = Bbuf[t & 1];
    bh8 a0[4][2], a1[4][2], b0[2][2], b1[2];
    // phase 0: read A-half0 + B-half0, stage (t+1) B1
#pragma unroll
    for (int mi = 0; mi < 4; ++mi) {
      const int row = (2 * mi + wr) * 16 + lr;
      a0[mi][0] = *(const bh8*)&Ab[row * 64 + sl0];
      a0[mi][1] = *(const bh8*)&Ab[row * 64 + sl1];
    }
#pragma unroll
    for (int ni = 0; ni < 2; ++ni) {
      const int row = (4 * ni + wc) * 16 + lr;
      b0[ni][0] = *(const bh8*)&Bb[row * 64 + sl0];
      b0[ni][1] = *(const bh8*)&Bb[row * 64 + sl1];
    }
    if (t + 1 < nt) stB1(t + 1);
    LGKM8;
    BAR;
    LGKM0; SBAR0;
    __builtin_amdgcn_s_setprio(1);
#pragma unroll
    for (int mi = 0; mi < 4; ++mi)
#pragma unroll
      for (int ni = 0; ni < 2; ++ni) {
        acc[mi][ni] = mfma16(a0[mi][0], b0[ni][0], acc[mi][ni]);
        acc[mi][ni] = mfma16(a0[mi][1], b0[ni][1], acc[mi][ni]);
      }
    __builtin_amdgcn_s_setprio(0);
    BAR;
    // phase 1: read A-half1, stage (t+2) A0
#pragma unroll
    for (int mi = 0; mi < 4; ++mi) {
      const int row = (2 * (mi + 4) + wr) * 16 + lr;
      a1[mi][0] = *(const bh8*)&Ab[row * 64 + sl0];
      a1[mi][1] = *(const bh8*)&Ab[row * 64 + sl1];
    }
    if (t + 2 < nt) stA(t + 2, 0);
    BAR;
    LGKM0; SBAR0;
    __builtin_amdgcn_s_setprio(1);
#pragma unroll
    for (int mi = 0; mi < 4; ++mi)
#pragma unroll
      for (int ni = 0; ni < 2; ++ni) {
        acc[mi + 4][ni] = mfma16(a1[mi][0], b0[ni][0], acc[mi + 4][ni]);
        acc[mi + 4][ni] = mfma16(a1[mi][1], b0[ni][1], acc[mi + 4][ni]);
      }
    __builtin_amdgcn_s_setprio(0);
    BAR;
    // phase 2: read B-half1 (ni=2), stage (t+2) A1
    {
      const int row = (8 + wc) * 16 + lr;
      b1[0] = *(const bh8*)&Bb[row * 64 + sl0];
      b1[1] = *(const bh8*)&Bb[row * 64 + sl1];
    }
    if (t + 2 < nt) stA(t + 2, 1);
    BAR;
    LGKM0; SBAR0;
    __builtin_amdgcn_s_setprio(1);
#pragma unroll
    for (int mi = 0; mi < 4; ++mi) {
      acc[mi][2] = mfma16(a0[mi][0], b1[0], acc[mi][2]);
      acc[mi][2] = mfma16(a0[mi][1], b1[1], acc[mi][2]);
    }
    __builtin_amdgcn_s_setprio(0);
    BAR;
    // phase 3: no reads, stage (t+2) B0, boundary vmcnt
    if (t + 2 < nt) stB0(t + 2);
    BAR;
    SBAR0;
    __builtin_amdgcn_s_setprio(1);
#pragma unroll
    for (int mi = 0; mi < 4; ++mi) {
      acc[mi + 4][2] = mfma16(a1[mi][0], b1[0], acc[mi + 4][2]);
      acc[mi + 4][2] = mfma16(a1[mi][1], b1[1], acc[mi + 4][2]);
    }
    __builtin_amdgcn_s_setprio(0);
    if (t + 1 < nt) {
      if (t + 2 < nt) { WAITV(6); } else { WAITV(0); }
      BAR;
    }
  }

  // epilogue: per-frag branch on 16-aligned base column
#pragma unroll
  for (int mi = 0; mi < 8; ++mi)
#pragma unroll
    for (int ni = 0; ni < 3; ++ni) {
      const int colb = (int)col0 + (4 * ni + wc) * 16;
      const int col = colb + lr;
      float bb = bias[col];
      if (colb >= 2048) {       // V -> Vt[(b*16+h)*64+dh][t]
        int cc = col - 2048;
        long row = row0 + (2 * mi + wr) * 16 + lh4;
        int bi = (int)(row >> 10), tt = (int)(row & 1023);
        ushort4 o;
        o.x = f2b(acc[mi][ni][0] + bb);
        o.y = f2b(acc[mi][ni][1] + bb);
        o.z = f2b(acc[mi][ni][2] + bb);
        o.w = f2b(acc[mi][ni][3] + bb);
        *(ushort4*)&Vtout[((size_t)(bi * 16 + (cc >> 6)) * 64 + (cc & 63)) *
                              1024 + tt] = o;
      } else {
        const float qsc = (colb < 1024) ? 0.03125f : 1.0f;
#pragma unroll
        for (int r = 0; r < 4; ++r) {
          long row = row0 + (2 * mi + wr) * 16 + lh4 + r;
          Cout[row * N + col] = f2b((acc[mi][ni][r] + bb) * qsc);
        }
      }
    }
}

// ------------------- fp8 8-phase 256x256 GEMM, BK=128 (FF1 / FF2)
// Inputs x16-scaled AND k-permuted (perm128) -> lane's 4 K=32 fragments are
// 32 contiguous LDS bytes = TWO ds_read_b128 (same instr count & bank
// pattern as the proven bf16 path). nt = K/128.
template <bool PART>
__global__ __launch_bounds__(512, 1) void gemm256f8(
    const unsigned char* __restrict__ A, const unsigned char* __restrict__ Bt,
    const float* __restrict__ bias, void* __restrict__ Cout,
    long N, long Kloop, long lda, long ldb, int MT, int NT, int CM, int CN) {
  __shared__ unsigned char Abuf[2][256 * 128];   // 64KB
  __shared__ unsigned char Bbuf[2][256 * 128];   // 64KB
  const int tid = threadIdx.x, lane = tid & 63, w = tid >> 6;
  const int wr = w >> 2, wc = w & 3;
  const int lr = lane & 15, lh = lane >> 4, lh4 = lh * 4;

  const int x = (int)blockIdx.x & 7, j = (int)blockIdx.x >> 3;
  const int gM = MT / CM;
  const int rowT = (x % gM) * CM + (j % CM);
  const int c = (x / gM) * CN + (j / CM);
  const int colT = c % NT, ksl = c / NT;
  const long row0 = (long)rowT * 256, col0 = (long)colT * 256;
  const long kOff = (long)ksl * Kloop;

  f4v acc[8][4];
#pragma unroll
  for (int i = 0; i < 8; ++i)
#pragma unroll
    for (int jj = 0; jj < 4; ++jj) acc[i][jj] = f4v{0.f, 0.f, 0.f, 0.f};

  const int rg = tid >> 3, sIdx = tid & 7;
  const int ch = sIdx ^ (rg & 7);
  const unsigned char* Ap = A + (row0 + rg) * lda + kOff + ch * 16;
  const unsigned char* Bp = Bt + (col0 + rg) * ldb + kOff + ch * 16;

  auto stA = [&](int t, int h) {
    const long k0 = (long)t << 7;
#pragma unroll
    for (int i = 0; i < 2; ++i)
      gld16(Ap + (long)(h * 128 + i * 64) * lda + k0,
            &Abuf[t & 1][(h * 128 + i * 64) * 128 + tid * 16]);
  };
  auto stB = [&](int t, int h) {
    const long k0 = (long)t << 7;
#pragma unroll
    for (int i = 0; i < 2; ++i)
      gld16(Bp + (long)(h * 128 + i * 64) * ldb + k0,
            &Bbuf[t & 1][(h * 128 + i * 64) * 128 + tid * 16]);
  };

  const int nt = (int)(Kloop >> 7);              // 8 for K=1024
  stA(0, 0); stA(0, 1); stB(0, 0); stB(0, 1);
  stA(1, 0); stA(1, 1); stB(1, 0);
  WAITV(6);
  BAR;

  // permuted layout: lane (lr,lh) reads chunks {2lh, 2lh+1} (16B each);
  // slot = chunk ^ (row&7), row&7 == lr&7 (rows 16-aligned + lr)
  const int c0b = ((lh * 2) ^ (lr & 7)) * 16;
  const int c1b = ((lh * 2 + 1) ^ (lr & 7)) * 16;

  for (int t = 0; t < nt; ++t) {
    const unsigned char* Ab = Abuf[t & 1];
    const unsigned char* Bb = Bbuf[t & 1];
    long a0[4][4], a1[4][4], b0[2][4], b1[2][4];
    // phase 0: A-half0 + B-half0 (12 b128 reads), stage (t+1) B1
#pragma unroll
    for (int mi = 0; mi < 4; ++mi) {
      const unsigned char* rp = &Ab[((2 * mi + wr) * 16 + lr) * 128];
      lg2 q0 = *(const lg2*)&rp[c0b];
      lg2 q1 = *(const lg2*)&rp[c1b];
      a0[mi][0] = q0[0]; a0[mi][1] = q0[1]; a0[mi][2] = q1[0]; a0[mi][3] = q1[1];
    }
#pragma unroll
    for (int ni = 0; ni < 2; ++ni) {
      const unsigned char* rp = &Bb[((4 * ni + wc) * 16 + lr) * 128];
      lg2 q0 = *(const lg2*)&rp[c0b];
      lg2 q1 = *(const lg2*)&rp[c1b];
      b0[ni][0] = q0[0]; b0[ni][1] = q0[1]; b0[ni][2] = q1[0]; b0[ni][3] = q1[1];
    }
    if (t + 1 < nt) stB(t + 1, 1);
    LGKM8;
    BAR;
    LGKM0; SBAR0;
    __builtin_amdgcn_s_setprio(1);
#pragma unroll
    for (int ks = 0; ks < 4; ++ks)
#pragma unroll
      for (int mi = 0; mi < 4; ++mi)
#pragma unroll
        for (int ni = 0; ni < 2; ++ni)
          acc[mi][ni] = mfma8(a0[mi][ks], b0[ni][ks], acc[mi][ni]);
    __builtin_amdgcn_s_setprio(0);
    BAR;
    // phase 1: A-half1 (8 reads), stage (t+2) A0
#pragma unroll
    for (int mi = 0; mi < 4; ++mi) {
      const unsigned char* rp = &Ab[((2 * (mi + 4) + wr) * 16 + lr) * 128];
      lg2 q0 = *(const lg2*)&rp[c0b];
      lg2 q1 = *(const lg2*)&rp[c1b];
      a1[mi][0] = q0[0]; a1[mi][1] = q0[1]; a1[mi][2] = q1[0]; a1[mi][3] = q1[1];
    }
    if (t + 2 < nt) stA(t + 2, 0);
    BAR;
    LGKM0; SBAR0;
    __builtin_amdgcn_s_setprio(1);
#pragma unroll
    for (int ks = 0; ks < 4; ++ks)
#pragma unroll
      for (int mi = 0; mi < 4; ++mi)
#pragma unroll
        for (int ni = 0; ni < 2; ++ni)
          acc[mi + 4][ni] = mfma8(a1[mi][ks], b0[ni][ks], acc[mi + 4][ni]);
    __builtin_amdgcn_s_setprio(0);
    BAR;
    // phase 2: B-half1 (4 reads), stage (t+2) A1
#pragma unroll
    for (int ni = 0; ni < 2; ++ni) {
      const unsigned char* rp = &Bb[((4 * (ni + 2) + wc) * 16 + lr) * 128];
      lg2 q0 = *(const lg2*)&rp[c0b];
      lg2 q1 = *(const lg2*)&rp[c1b];
      b1[ni][0] = q0[0]; b1[ni][1] = q0[1]; b1[ni][2] = q1[0]; b1[ni][3] = q1[1];
    }
    if (t + 2 < nt) stA(t + 2, 1);
    BAR;
    LGKM0; SBAR0;
    __builtin_amdgcn_s_setprio(1);
#pragma unroll
    for (int ks = 0; ks < 4; ++ks)
#pragma unroll
      for (int mi = 0; mi < 4; ++mi)
#pragma unroll
        for (int ni = 0; ni < 2; ++ni)
          acc[mi][ni + 2] = mfma8(a0[mi][ks], b1[ni][ks], acc[mi][ni + 2]);
    __builtin_amdgcn_s_setprio(0);
    BAR;
    // phase 3: no reads, stage (t+2) B0, boundary vmcnt
    if (t + 2 < nt) stB(t + 2, 0);
    BAR;
    SBAR0;
    __builtin_amdgcn_s_setprio(1);
#pragma unroll
    for (int ks = 0; ks < 4; ++ks)
#pragma unroll
      for (int mi = 0; mi < 4; ++mi)
#pragma unroll
        for (int ni = 0; ni < 2; ++ni)
          acc[mi + 4][ni + 2] = mfma8(a1[mi][ks], b1[ni][ks], acc[mi + 4][ni + 2]);
    __builtin_amdgcn_s_setprio(0);
    if (t + 1 < nt) {
      if (t + 2 < nt) { WAITV(6); } else { WAITV(0); }
      BAR;
    }
  }

  constexpr float DS = 1.f / 256.f;
  if (PART) {   // FF2: bf16 partial plane (bias added in ln2_fuse), N linear
    unsigned short* P = (unsigned short*)Cout + (size_t)ksl * 4096 * 1024;
#pragma unroll
    for (int mi = 0; mi < 8; ++mi)
#pragma unroll
      for (int ni = 0; ni < 4; ++ni) {
        long col = col0 + (4 * ni + wc) * 16 + lr;
#pragma unroll
        for (int r = 0; r < 4; ++r) {
          long row = row0 + (2 * mi + wr) * 16 + lh4 + r;
          P[row * N + col] = f2b(acc[mi][ni][r] * DS);
        }
      }
    return;
  }
  // FF1: relu(acc/256 + b1) -> e4m3(v*16) at k-PERMUTED column (feeds FF2)
#pragma unroll
  for (int mi = 0; mi < 8; ++mi)
#pragma unroll
    for (int ni = 0; ni < 4; ++ni) {
      const int col = (int)col0 + (4 * ni + wc) * 16 + lr;
      float bb = bias[col];
      const int colp = perm128(col);
#pragma unroll
      for (int r = 0; r < 4; ++r) {
        long row = row0 + (2 * mi + wr) * 16 + lh4 + r;
        float v = fmaxf(acc[mi][ni][r] * DS + bb, 0.f);
        ((unsigned char*)Cout)[row * N + colp] = f2e4m3(v * 16.f);
      }
    }
}

// ------------------------------------------- small GEMM (logits), round-5 form
template <int TM, int TN, bool RELU, bool F32OUT>
__global__ __launch_bounds__(256) void gemm4(
    const unsigned short* __restrict__ A, const unsigned short* __restrict__ Bt,
    const float* __restrict__ bias, void* __restrict__ Cout, long N, long K) {
  constexpr int MI = TM / 32, NI = TN / 32;
  constexpr int ABUF = TM * 64, BBUF = TN * 64;
  __shared__ unsigned short As[2 * ABUF];
  __shared__ unsigned short Bs[2 * BBUF];
  const int tid = threadIdx.x;
  const int lane = tid & 63, w = tid >> 6;
  const int wr = w >> 1, wc = w & 1;
  const int lr = lane & 15, lh = lane >> 4, lh4 = lh * 4;
  const long row0 = (long)blockIdx.x * TM, col0 = (long)blockIdx.y * TN;
  f4v acc[MI][NI];
#pragma unroll
  for (int i = 0; i < MI; ++i)
#pragma unroll
    for (int j = 0; j < NI; ++j) acc[i][j] = f4v{0.f, 0.f, 0.f, 0.f};
  const int rg = tid >> 3, s = tid & 7;
  const int ch = s ^ (rg & 7);
  const unsigned short* Ap = A + (row0 + rg) * K + ch * 8;
  const unsigned short* Bp = Bt + (col0 + rg) * K + ch * 8;
  auto stage = [&](int t, int buf) {
    const long k0 = (long)t << 6;
#pragma unroll
    for (int i = 0; i < MI; ++i)
      gld16(Ap + i * 32 * K + k0, &As[buf * ABUF + (i * 256 + tid) * 8]);
#pragma unroll
    for (int i = 0; i < NI; ++i)
      gld16(Bp + i * 32 * K + k0, &Bs[buf * BBUF + (i * 256 + tid) * 8]);
  };
  const int nt = (int)(K >> 6);
  stage(0, 0);
  for (int t = 0; t < nt; ++t) {
    const int cur = t & 1;
    if (t + 1 < nt) {
      stage(t + 1, cur ^ 1);
      WAITV(6);
    } else {
      WAITV(0);
    }
    BAR;
    const unsigned short* Ab = &As[cur * ABUF];
    const unsigned short* Bb = &Bs[cur * BBUF];
#pragma unroll
    for (int ks = 0; ks < 2; ++ks) {
      bh8 a[MI], b[NI];
      const int slot = ((ks << 2) | lh) ^ (lr & 7);
#pragma unroll
      for (int mi = 0; mi < MI; ++mi) {
        int m = wr * (TM / 2) + mi * 16 + lr;
        a[mi] = *(const bh8*)((const char*)Ab + m * 128 + slot * 16);
      }
#pragma unroll
      for (int ni = 0; ni < NI; ++ni) {
        int n = wc * (TN / 2) + ni * 16 + lr;
        b[ni] = *(const bh8*)((const char*)Bb + n * 128 + slot * 16);
      }
#pragma unroll
      for (int mi = 0; mi < MI; ++mi)
#pragma unroll
        for (int ni = 0; ni < NI; ++ni)
          acc[mi][ni] = mfma16(a[mi], b[ni], acc[mi][ni]);
    }
    BAR;
  }
#pragma unroll
  for (int mi = 0; mi < MI; ++mi) {
#pragma unroll
    for (int ni = 0; ni < NI; ++ni) {
      long col = col0 + wc * (TN / 2) + ni * 16 + lr;
      float bb = bias[col];
#pragma unroll
      for (int r = 0; r < 4; ++r) {
        long row = row0 + wr * (TM / 2) + mi * 16 + lh4 + r;
        float v = acc[mi][ni][r] + bb;
        if (RELU) v = fmaxf(v, 0.f);
        if (F32OUT) ((float*)Cout)[row * N + col] = v;
        else ((unsigned short*)Cout)[row * N + col] = f2b(v);
      }
    }
  }
}

// ------------------------------------------------- flash attention (MFMA)
// QBLK=128 x KVBLK=128, 8 waves; r13-verified structure.
__global__ __launch_bounds__(512) void attn_mfma(
    const unsigned short* __restrict__ QKV, const unsigned short* __restrict__ Vt,
    unsigned short* __restrict__ Hout) {
  __shared__ unsigned short Ks[2][128 * 64];   // [key][dh] swizzled, 32KB
  __shared__ unsigned short Vs[2][2][64 * 64]; // [half][dh][key] swizzled, 32KB
  __shared__ unsigned short Ps[8][16 * 64];    // per-wave [q][key-half], 16KB
  const int tid = threadIdx.x, w = tid >> 6, lane = tid & 63;
  const int wid = ((int)blockIdx.x & 7) * 64 + ((int)blockIdx.x >> 3);
  const int bh = wid >> 3;                     // 8 consecutive bh per XCD
  const int qt = 7 - (wid & 7);                // heavy q-blocks first
  const int b = bh >> 4, h = bh & 15;
  const int lr = lane & 15, lh = lane >> 4, lh4 = lh * 4;

  const unsigned short* qp =
      QKV + (size_t)(b * 1024 + qt * 128 + w * 16 + lr) * 3072 + h * 64 + lh * 8;
  bh8 aq0 = *(const bh8*)qp;
  bh8 aq1 = *(const bh8*)(qp + 32);

  f4v o[4];
#pragma unroll
  for (int i = 0; i < 4; ++i) o[i] = f4v{0.f, 0.f, 0.f, 0.f};
  float m = -1e30f, l = 0.f;

  const int r8 = tid >> 3, slot = tid & 7;     // r8 0..63
  unsigned short* pw = &Ps[w][0];

  auto stage = [&](int kt, int buf) {
    int c8 = (slot ^ (r8 & 7)) * 8;
    gld16(QKV + (size_t)(b * 1024 + kt * 128 + r8) * 3072 + 1024 + h * 64 + c8,
          &Ks[buf][tid * 8]);
    int r2 = r8 + 64;
    int c82 = (slot ^ (r2 & 7)) * 8;
    gld16(QKV + (size_t)(b * 1024 + kt * 128 + r2) * 3072 + 1024 + h * 64 + c82,
          &Ks[buf][64 * 64 + tid * 8]);
    gld16(Vt + (size_t)(bh * 64 + r8) * 1024 + kt * 128 + c8, &Vs[buf][0][tid * 8]);
    gld16(Vt + (size_t)(bh * 64 + r8) * 1024 + kt * 128 + 64 + c8,
          &Vs[buf][1][tid * 8]);
  };

  stage(0, 0);

  for (int kt = 0; kt <= qt; ++kt) {
    const int cur = kt & 1;
    if (kt < qt) {
      stage(kt + 1, cur ^ 1);
      WAITV(4);
    } else {
      WAITV(0);
    }
    BAR;

    f4v s[8];
#pragma unroll
    for (int nt = 0; nt < 8; ++nt) {
      bh8 k0 = lds_swz(Ks[cur], nt * 16 + lr, lh * 16);
      bh8 k1 = lds_swz(Ks[cur], nt * 16 + lr, lh * 16 + 64);
      f4v z = f4v{0.f, 0.f, 0.f, 0.f};
      z = mfma16(k0, aq0, z);
      z = mfma16(k1, aq1, z);
      s[nt] = z;
    }
    if (kt == qt) {
      const int qloc = w * 16 + lr;
#pragma unroll
      for (int nt = 0; nt < 8; ++nt)
#pragma unroll
        for (int r = 0; r < 4; ++r)
          if ((nt * 16 + lh4 + r) > qloc) s[nt][r] = -1e30f;
    }
    float tm = s[0][0];
#pragma unroll
    for (int nt = 0; nt < 8; ++nt)
#pragma unroll
      for (int r = 0; r < 4; ++r) tm = fmaxf(tm, s[nt][r]);
    tm = fmaxf(tm, __shfl_xor(tm, 16));
    tm = fmaxf(tm, __shfl_xor(tm, 32));

    const bool resc = __any(tm > m + 8.f);     // defer-max (T13)
    const float mu = resc ? fmaxf(m, tm) : m;
    float sum = 0.f;
#pragma unroll
    for (int nt = 0; nt < 8; ++nt)
#pragma unroll
      for (int r = 0; r < 4; ++r) {
        float e = __expf(s[nt][r] - mu);
        s[nt][r] = e;
        sum += e;
      }
    sum += __shfl_xor(sum, 16);
    sum += __shfl_xor(sum, 32);
    if (resc) {
      float corr = __expf(m - mu);
      m = mu;
      l = l * corr + sum;
      float c0 = __shfl(corr, lh4 + 0), c1 = __shfl(corr, lh4 + 1);
      float c2 = __shfl(corr, lh4 + 2), c3 = __shfl(corr, lh4 + 3);
#pragma unroll
      for (int nt = 0; nt < 4; ++nt) {
        o[nt][0] *= c0; o[nt][1] *= c1; o[nt][2] *= c2; o[nt][3] *= c3;
      }
    } else {
      l += sum;
    }
#pragma unroll
    for (int hh = 0; hh < 2; ++hh) {
#pragma unroll
      for (int q = 0; q < 4; ++q) {
        const int nt = hh * 4 + q;
        unsigned int u0, u1;
        asm("v_cvt_pk_bf16_f32 %0, %1, %2" : "=v"(u0) : "v"(s[nt][0]), "v"(s[nt][1]));
        asm("v_cvt_pk_bf16_f32 %0, %1, %2" : "=v"(u1) : "v"(s[nt][2]), "v"(s[nt][3]));
        uint2 pk{u0, u1};
        *(uint2*)((char*)pw + lr * 128 + ((q * 32 + lh * 8) ^ ((lr & 7) << 4))) = pk;
      }
      bh8 pa0 = lds_swz(pw, lr, lh * 16);
      bh8 pa1 = lds_swz(pw, lr, lh * 16 + 64);
      const unsigned short* Vh = Vs[cur][hh];
#pragma unroll
      for (int nt2 = 0; nt2 < 4; ++nt2) {
        bh8 v0 = lds_swz(Vh, nt2 * 16 + lr, lh * 16);
        bh8 v1 = lds_swz(Vh, nt2 * 16 + lr, lh * 16 + 64);
        o[nt2] = mfma16(pa0, v0, o[nt2]);
        o[nt2] = mfma16(pa1, v1, o[nt2]);
      }
    }
    BAR;
  }
  float linv = 1.f / l;
  float l0 = __shfl(linv, lh4 + 0), l1 = __shfl(linv, lh4 + 1);
  float l2 = __shfl(linv, lh4 + 2), l3 = __shfl(linv, lh4 + 3);
  const size_t rowb = (size_t)(b * 1024 + qt * 128 + w * 16);
#pragma unroll
  for (int nt = 0; nt < 4; ++nt) {
    int col = h * 64 + nt * 16 + lr;
    Hout[(rowb + lh4 + 0) * 1024 + col] = f2b(o[nt][0] * l0);
    Hout[(rowb + lh4 + 1) * 1024 + col] = f2b(o[nt][1] * l1);
    Hout[(rowb + lh4 + 2) * 1024 + col] = f2b(o[nt][2] * l2);
    Hout[(rowb + lh4 + 3) * 1024 + col] = f2b(o[nt][3] * l3);
  }
}

// ----------------- y = x + layer_norm(x); FP8: emit e4m3(y*16) k-PERMUTED
template <bool FP8>
__global__ __launch_bounds__(256) void ln_res_bf(
    const unsigned short* __restrict__ Xi, const float* __restrict__ wln,
    void* __restrict__ Y) {
  int row = blockIdx.x, tid = threadIdx.x;
  ushort4 u = ((const ushort4*)(Xi + (size_t)row * 1024))[tid];
  float x0 = b2f(u.x), x1 = b2f(u.y), x2 = b2f(u.z), x3 = b2f(u.w);
  float s = x0 + x1 + x2 + x3;
  float ss = x0 * x0 + x1 * x1 + x2 * x2 + x3 * x3;
#pragma unroll
  for (int off = 32; off; off >>= 1) {
    s += __shfl_xor(s, off);
    ss += __shfl_xor(ss, off);
  }
  __shared__ float sw[4], ssw[4];
  int wv = tid >> 6, ln = tid & 63;
  if (ln == 0) { sw[wv] = s; ssw[wv] = ss; }
  __syncthreads();
  s = sw[0] + sw[1] + sw[2] + sw[3];
  ss = ssw[0] + ssw[1] + ssw[2] + ssw[3];
  float mean = s * (1.f / 1024.f);
  float var = ss * (1.f / 1024.f) - mean * mean;
  float rstd = rsqrtf(var + 1e-5f);
  float4 wv4 = ((const float4*)wln)[tid];
  float y0 = x0 + (x0 - mean) * rstd * wv4.x;
  float y1 = x1 + (x1 - mean) * rstd * wv4.y;
  float y2 = x2 + (x2 - mean) * rstd * wv4.z;
  float y3 = x3 + (x3 - mean) * rstd * wv4.w;
  if (FP8) {
    *(unsigned int*)((unsigned char*)Y + (size_t)row * 1024 + perm128(tid * 4)) =
        pk4_e4m3(y0 * 16.f, y1 * 16.f, y2 * 16.f, y3 * 16.f);
  } else {
    ushort4 out;
    out.x = f2b(y0); out.y = f2b(y1); out.z = f2b(y2); out.w = f2b(y3);
    ((ushort4*)Y)[row * 256 + tid] = out;
  }
}

// ---------------- FF2 split-K reduce + bias + (x + layer_norm(x)) fused
__global__ __launch_bounds__(256) void ln2_fuse(
    const unsigned short* __restrict__ P, const float* __restrict__ b2,
    const float* __restrict__ wln, unsigned short* __restrict__ Y) {
  int row = blockIdx.x, tid = threadIdx.x;
  const size_t plane = (size_t)4096 * 1024;
  float x0 = 0.f, x1 = 0.f, x2 = 0.f, x3 = 0.f;
#pragma unroll
  for (int pl = 0; pl < 4; ++pl) {
    ushort4 u = *(const ushort4*)&P[pl * plane + (size_t)row * 1024 + tid * 4];
    x0 += b2f(u.x); x1 += b2f(u.y); x2 += b2f(u.z); x3 += b2f(u.w);
  }
  float4 bb = ((const float4*)b2)[tid];
  x0 += bb.x; x1 += bb.y; x2 += bb.z; x3 += bb.w;
  float s = x0 + x1 + x2 + x3;
  float ss = x0 * x0 + x1 * x1 + x2 * x2 + x3 * x3;
#pragma unroll
  for (int off = 32; off; off >>= 1) {
    s += __shfl_xor(s, off);
    ss += __shfl_xor(ss, off);
  }
  __shared__ float sw[4], ssw[4];
  int wv = tid >> 6, ln = tid & 63;
  if (ln == 0) { sw[wv] = s; ssw[wv] = ss; }
  __syncthreads();
  s = sw[0] + sw[1] + sw[2] + sw[3];
  ss = ssw[0] + ssw[1] + ssw[2] + ssw[3];
  float mean = s * (1.f / 1024.f);
  float var = ss * (1.f / 1024.f) - mean * mean;
  float rstd = rsqrtf(var + 1e-5f);
  float4 wv4 = ((const float4*)wln)[tid];
  ushort4 out;
  out.x = f2b(x0 + (x0 - mean) * rstd * wv4.x);
  out.y = f2b(x1 + (x1 - mean) * rstd * wv4.y);
  out.z = f2b(x2 + (x2 - mean) * rstd * wv4.z);
  out.w = f2b(x3 + (x3 - mean) * rstd * wv4.w);
  ((ushort4*)(Y + (size_t)row * 1024))[tid] = out;
}

// ------------------------------------------- probs = softmax over T axis
__global__ __launch_bounds__(256) void softmaxT_kernel(
    const float* __restrict__ logits, float* __restrict__ probs) {
  int b = blockIdx.x / VOC;
  int v = blockIdx.x - b * VOC;
  const float* src = logits + (size_t)b * 1024 * 128 + v;
  float vals[4];
  float m = -1e30f;
#pragma unroll
  for (int i = 0; i < 4; ++i) {
    int t = threadIdx.x + 256 * i;
    vals[i] = src[(size_t)t * 128];
    m = fmaxf(m, vals[i]);
  }
#pragma unroll
  for (int off = 32; off; off >>= 1) m = fmaxf(m, __shfl_xor(m, off));
  __shared__ float sm[4], ssum[4];
  int wv = threadIdx.x >> 6, ln = threadIdx.x & 63;
  if (ln == 0) sm[wv] = m;
  __syncthreads();
  m = fmaxf(fmaxf(sm[0], sm[1]), fmaxf(sm[2], sm[3]));
  float s = 0.f;
#pragma unroll
  for (int i = 0; i < 4; ++i) { vals[i] = __expf(vals[i] - m); s += vals[i]; }
#pragma unroll
  for (int off = 32; off; off >>= 1) s += __shfl_xor(s, off);
  if (ln == 0) ssum[wv] = s;
  __syncthreads();
  s = ssum[0] + ssum[1] + ssum[2] + ssum[3];
  float inv = 1.f / s;
  float* dst = probs + (size_t)b * 1024 * VOC + v;
#pragma unroll
  for (int i = 0; i < 4; ++i) {
    int t = threadIdx.x + 256 * i;
    dst[(size_t)t * VOC] = vals[i] * inv;
  }
}

// ------------------------- per-row -log_softmax_V(probs)[target] partials
__global__ __launch_bounds__(256) void loss_rows_kernel(
    const float* __restrict__ probs, const int* __restrict__ tgt,
    float* __restrict__ partial) {
  int wv = threadIdx.x >> 6, lane = threadIdx.x & 63;
  int row = blockIdx.x * 4 + wv;
  const float* p = probs + (size_t)row * VOC;
  float x0 = p[lane];
  float x1 = (lane == 0) ? p[64] : -1e30f;
  float m = fmaxf(x0, x1);
#pragma unroll
  for (int off = 32; off; off >>= 1) m = fmaxf(m, __shfl_xor(m, off));
  float s = __expf(x0 - m) + ((lane == 0) ? __expf(x1 - m) : 0.f);
#pragma unroll
  for (int off = 32; off; off >>= 1) s += __shfl_xor(s, off);
  if (lane == 0) {
    int tg = tgt[row];
    partial[row] = (p[tg] - m) - logf(s);
  }
}

__global__ __launch_bounds__(256) void loss_final_kernel(
    const float* __restrict__ partial, float* __restrict__ out) {
  float s = 0.f;
  for (int i = threadIdx.x; i < Mrow; i += 256) s += partial[i];
#pragma unroll
  for (int off = 32; off; off >>= 1) s += __shfl_xor(s, off);
  __shared__ float sw[4];
  int wv = threadIdx.x >> 6, ln = threadIdx.x & 63;
  if (ln == 0) sw[wv] = s;
  __syncthreads();
  if (threadIdx.x == 0) out[0] = -(sw[0] + sw[1] + sw[2] + sw[3]) / (float)Mrow;
}

// ------------------------------------------------------------------ launch
extern "C" void kernel_launch(void* const* d_in, const int* in_sizes, int n_in,
                              void* d_out, int out_size, void* d_ws,
                              size_t ws_size, hipStream_t stream) {
  (void)in_sizes; (void)n_in; (void)out_size; (void)ws_size;
  const int*   tok    = (const int*)d_in[0];
  const int*   target = (const int*)d_in[1];
  const float* Wtok   = (const float*)d_in[3];
  const float* Wpos   = (const float*)d_in[4];
  const float* Wq = (const float*)d_in[5];  const float* bq = (const float*)d_in[6];
  const float* Wk = (const float*)d_in[7];  const float* bk = (const float*)d_in[8];
  const float* Wv = (const float*)d_in[9];  const float* bv = (const float*)d_in[10];
  const float* W1 = (const float*)d_in[11]; const float* b1 = (const float*)d_in[12];
  const float* W2 = (const float*)d_in[13]; const float* b2 = (const float*)d_in[14];
  const float* lnw = (const float*)d_in[15];
  const float* Wf = (const float*)d_in[16]; const float* bf = (const float*)d_in[17];
  float* out = (float*)d_out;

  char* p = (char*)d_ws;
  unsigned short* Xb    = (unsigned short*)p; p += (size_t)Mrow * 1024 * 2;
  unsigned short* QKVb  = (unsigned short*)p; p += (size_t)Mrow * 3072 * 2;
  unsigned short* Vt    = (unsigned short*)p; p += (size_t)64 * 64 * 1024 * 2;
  unsigned short* Hb    = (unsigned short*)p; p += (size_t)Mrow * 1024 * 2;
  unsigned char*  F2b8  = (unsigned char*)p;  p += (size_t)Mrow * 1024;
  unsigned char*  FF1b8 = (unsigned char*)p;  p += (size_t)Mrow * 4096;
  unsigned short* WqkvT = (unsigned short*)p; p += (size_t)3072 * 1024 * 2;
  unsigned char*  W1T8  = (unsigned char*)p;  p += (size_t)4096 * 1024;
  unsigned char*  W2T8  = (unsigned char*)p;  p += (size_t)1024 * 4096;
  unsigned short* WfT   = (unsigned short*)p; p += (size_t)128 * 1024 * 2;
  float* bqkv = (float*)p; p += 3072 * 4;
  float* bfp  = (float*)p; p += 128 * 4;
  float* LOG  = (float*)p; p += (size_t)Mrow * 128 * 4;
  float* PART = (float*)p; p += Mrow * 4;
  // FF2 split-K bf16 partials: alias dead-at-FF2-time QKVb+Vt (32 MB)
  unsigned short* Pff2 = QKVb;

  wt_conv<<<dim3(32, 32), 256, 0, stream>>>(Wq, WqkvT,                1024, 1024);
  wt_conv<<<dim3(32, 32), 256, 0, stream>>>(Wk, WqkvT + 1024 * 1024,  1024, 1024);
  wt_conv<<<dim3(32, 32), 256, 0, stream>>>(Wv, WqkvT + 2048 * 1024,  1024, 1024);
  wt_conv8<<<dim3(32, 128), 256, 0, stream>>>(W1, W1T8, 1024, 4096);
  wt_conv8<<<dim3(128, 32), 256, 0, stream>>>(W2, W2T8, 4096, 1024);
  wt_conv<<<dim3(32, 4), 256, 0, stream>>>(Wf, WfT, 1024, VOC);
  bias_prep<<<13, 256, 0, stream>>>(bq, bk, bv, bf, bqkv, bfp);

  embed_bf<<<Mrow, 256, 0, stream>>>(tok, Wtok, Wpos, Xb);

  for (int l = 0; l < NL; ++l) {
    // QKV bf16: 256x192 8-phase, grid 256 = 1 block/CU EXACT (chunk 4x8)
    gemm192<<<256, 512, 0, stream>>>(
        Xb, WqkvT, bqkv, QKVb, Vt, 3072, 1024, 16, 4, 8);
    // attention: QBLK=128, KVBLK=128, 8 waves, 512 blocks (2 blk/CU)
    attn_mfma<<<512, 512, 0, stream>>>(QKVb, Vt, Hb);
    ln_res_bf<true><<<Mrow, 256, 0, stream>>>(Hb, lnw, F2b8);     // h+ln(h), fp8p
    // FF1 fp8 (b128 frags): grid 256; out fp8 k-permuted for FF2
    gemm256f8<false><<<256, 512, 0, stream>>>(
        F2b8, W1T8, b1, FF1b8, 4096, 1024, 1024, 1024, 16, 16, 4, 8);
    // FF2 fp8: split-K4 (Kloop=1024), grid 256, bf16 partials
    gemm256f8<true><<<256, 512, 0, stream>>>(
        FF1b8, W2T8, nullptr, Pff2, 1024, 1024, 4096, 4096, 16, 4, 4, 8);
    ln2_fuse<<<Mrow, 256, 0, stream>>>(Pff2, b2, lnw, Xb);        // ff + ln(ff)
  }

  gemm4<64, 128, false, true><<<dim3(64, 1), 256, 0, stream>>>(
      Xb, WfT, bfp, LOG, 128, 1024);                              // logits (f32)
  softmaxT_kernel<<<4 * VOC, 256, 0, stream>>>(LOG, out + 1);
  loss_rows_kernel<<<Mrow / 4, 256, 0, stream>>>(out + 1, target, PART);
  loss_final_kernel<<<1, 256, 0, stream>>>(PART, out);
}